// Round 1
// baseline (196.972 us; speedup 1.0000x reference)
//
#include <hip/hip_runtime.h>
#include <cstddef>

// Problem constants (fixed by reference)
#define BB   8
#define CC   64
#define H1   128
#define W1   128
#define HS   60
#define WS   60
#define HO   129   // conv output = H + 2*3 - 6 + 1
#define WO   129
#define TSTR 24    // padded LDS row stride (21 -> 24: exact 2-way bank aliasing, free)

// ---------------------------------------------------------------------------
// K1: inv-norm over channels of x1:  inv1[b,h,w] = 1/||x1[b,:,h,w]||
__global__ __launch_bounds__(256) void k_inv1(const float* __restrict__ x1,
                                              float* __restrict__ inv1) {
    int idx = blockIdx.x * 256 + threadIdx.x;   // B*H*W = 131072 exactly
    int b  = idx >> 14;                          // / (128*128)
    int hw = idx & 16383;
    const float* p = x1 + (size_t)b * CC * (H1 * W1) + hw;
    float s = 0.f;
#pragma unroll
    for (int c = 0; c < CC; ++c) {
        float v = p[c * (H1 * W1)];
        s += v * v;
    }
    inv1[idx] = 1.0f / sqrtf(s);
}

// K2a: inv-norm over channels of x2
__global__ __launch_bounds__(256) void k_inv2(const float* __restrict__ x2,
                                              float* __restrict__ inv2) {
    int idx = blockIdx.x * 256 + threadIdx.x;   // B*60*60 = 28800
    if (idx >= BB * HS * WS) return;
    int b  = idx / (HS * WS);
    int hw = idx % (HS * WS);
    const float* p = x2 + (size_t)b * CC * (HS * WS) + hw;
    float s = 0.f;
#pragma unroll
    for (int c = 0; c < CC; ++c) {
        float v = p[c * (HS * WS)];
        s += v * v;
    }
    inv2[idx] = 1.0f / sqrtf(s);
}

// K2b: fold the 10x10 patch grid of x2n into one 6x6 kernel per (b,c):
//      S[b,c,dy,dx] = sum_{i0,i1} x2n[b,c, i0*6+dy, i1*6+dx]
__global__ __launch_bounds__(256) void k_fold(const float* __restrict__ x2,
                                              const float* __restrict__ inv2,
                                              float* __restrict__ S) {
    int idx = blockIdx.x * 256 + threadIdx.x;   // B*C*36 = 18432
    if (idx >= BB * CC * 36) return;
    int k  = idx % 36;
    int bc = idx / 36;
    int b  = bc / CC;
    int dy = k / 6, dx = k % 6;
    const float* px = x2 + (size_t)bc * (HS * WS);
    const float* pn = inv2 + b * (HS * WS);
    float s = 0.f;
#pragma unroll
    for (int i0 = 0; i0 < 10; ++i0) {
#pragma unroll
        for (int i1 = 0; i1 < 10; ++i1) {
            int hh = i0 * 6 + dy, ww = i1 * 6 + dx;
            s += px[hh * WS + ww] * pn[hh * WS + ww];
        }
    }
    S[idx] = s;
}

// K3: per-batch correlation with the folded 6x6x64 kernel, "same+1" output
//     out129[b,y,x] = (1/3600) * sum_{c,dy,dx} x1n[b,c,y-3+dy,x-3+dx]*S[b,c,dy,dx]
__global__ __launch_bounds__(256) void k_conv(const float* __restrict__ x1,
                                              const float* __restrict__ inv1,
                                              const float* __restrict__ S,
                                              float* __restrict__ out129) {
    int blk = blockIdx.x;           // 9*9*8 = 648
    int bx  = blk % 9;
    int by  = (blk / 9) % 9;
    int b   = blk / 81;
    int tx  = threadIdx.x & 15;
    int ty  = threadIdx.x >> 4;
    int y0  = by * 16, x0 = bx * 16;

    __shared__ float tile[21 * TSTR];

    const float* x1b   = x1 + (size_t)b * CC * (H1 * W1);
    const float* inv1b = inv1 + b * (H1 * W1);
    const float* Sb    = S + b * CC * 36;

    float acc = 0.f;

    for (int c = 0; c < CC; ++c) {
        // stage normalized halo tile (21x21 logical) into LDS
        for (int i = threadIdx.x; i < 21 * 21; i += 256) {
            int iy = i / 21, ix = i % 21;
            int gy = y0 - 3 + iy, gx = x0 - 3 + ix;
            float v = 0.f;
            if (gy >= 0 && gy < H1 && gx >= 0 && gx < W1)
                v = x1b[c * (H1 * W1) + gy * W1 + gx] * inv1b[gy * W1 + gx];
            tile[iy * TSTR + ix] = v;
        }
        __syncthreads();

        const float* Sc = Sb + c * 36;   // uniform address -> scalar-cache loads
#pragma unroll
        for (int dy = 0; dy < 6; ++dy) {
#pragma unroll
            for (int dx = 0; dx < 6; ++dx) {
                acc += tile[(ty + dy) * TSTR + tx + dx] * Sc[dy * 6 + dx];
            }
        }
        __syncthreads();
    }

    int y = y0 + ty, x = x0 + tx;
    if (y < HO && x < WO)
        out129[(size_t)b * (HO * WO) + y * WO + x] = acc * (1.0f / 3600.0f);
}

// K4: jax.image.resize bilinear antialias=True, 129 -> 128, half-pixel
__global__ __launch_bounds__(256) void k_resize(const float* __restrict__ out129,
                                                float* __restrict__ out) {
    int idx = blockIdx.x * 256 + threadIdx.x;   // B*128*128 = 131072
    int b  = idx >> 14;
    int oy = (idx >> 7) & 127;
    int ox = idx & 127;

    const float inv_scale = 129.0f / 128.0f;    // input units per output unit
    const float ksc       = 128.0f / 129.0f;    // 1/kernel_scale (antialias widen)

    float sy = (oy + 0.5f) * inv_scale - 0.5f;
    float sx = (ox + 0.5f) * inv_scale - 0.5f;
    int fy = (int)floorf(sy);
    int fx = (int)floorf(sx);

    float wy[4], wx[4];
    float sumy = 0.f, sumx = 0.f;
#pragma unroll
    for (int k = 0; k < 4; ++k) {
        int jy = fy - 1 + k;
        float w = 0.f;
        if (jy >= 0 && jy < HO) w = fmaxf(0.f, 1.0f - fabsf(sy - (float)jy) * ksc);
        wy[k] = w; sumy += w;
        int jx = fx - 1 + k;
        float w2 = 0.f;
        if (jx >= 0 && jx < WO) w2 = fmaxf(0.f, 1.0f - fabsf(sx - (float)jx) * ksc);
        wx[k] = w2; sumx += w2;
    }

    const float* p = out129 + (size_t)b * (HO * WO);
    float r = 0.f;
#pragma unroll
    for (int ky = 0; ky < 4; ++ky) {
        if (wy[ky] == 0.f) continue;
        int jy = fy - 1 + ky;
        float rowv = 0.f;
#pragma unroll
        for (int kx = 0; kx < 4; ++kx) {
            if (wx[kx] == 0.f) continue;
            rowv += wx[kx] * p[jy * WO + (fx - 1 + kx)];
        }
        r += wy[ky] * rowv;
    }
    out[idx] = r / (sumy * sumx);
}

// ---------------------------------------------------------------------------
extern "C" void kernel_launch(void* const* d_in, const int* in_sizes, int n_in,
                              void* d_out, int out_size, void* d_ws, size_t ws_size,
                              hipStream_t stream) {
    const float* x1 = (const float*)d_in[0];   // (8,64,128,128)
    const float* x2 = (const float*)d_in[1];   // (8,64,60,60)
    float* out = (float*)d_out;                // (8,1,128,128) -> 131072 floats

    // workspace layout (floats)
    float* ws     = (float*)d_ws;
    float* inv1   = ws;                         // 131072
    float* inv2   = inv1 + BB * H1 * W1;        // 28800
    float* S      = inv2 + BB * HS * WS;        // 18432
    float* out129 = S + BB * CC * 36;           // 133128

    k_inv1<<<(BB * H1 * W1) / 256, 256, 0, stream>>>(x1, inv1);
    k_inv2<<<(BB * HS * WS + 255) / 256, 256, 0, stream>>>(x2, inv2);
    k_fold<<<(BB * CC * 36 + 255) / 256, 256, 0, stream>>>(x2, inv2, S);
    k_conv<<<9 * 9 * BB, 256, 0, stream>>>(x1, inv1, S, out129);
    k_resize<<<(BB * H1 * W1) / 256, 256, 0, stream>>>(out129, out);
}

// Round 2
// 134.855 us; speedup vs baseline: 1.4606x; 1.4606x over previous
//
#include <hip/hip_runtime.h>
#include <cstddef>

// Problem constants
#define BB   8
#define CC   64
#define H1   128
#define W1   128
#define HW1  (H1*W1)
#define HS   60
#define WS   60
#define HO   129
#define WO   129

// conv tiling
#define G     16            // channel groups
#define CPG   4             // channels per group (64/16)
#define HR    38            // halo rows  (32 outputs + 5 taps + 1 ext row)
#define HC    75            // halo cols used (64 outputs + 5 taps + ext col window)
#define HSTR  76            // padded LDS row stride (16B-aligned float4 reads)
#define NST   12            // ceil(38*75/256)
#define PSTR  132           // partial plane row stride (float4-aligned stores)
#define PPLANE (HO*PSTR)    // 17028

// ---------------------------------------------------------------------------
__global__ __launch_bounds__(256) void k_inv1(const float* __restrict__ x1,
                                              float* __restrict__ inv1) {
    int idx = blockIdx.x * 256 + threadIdx.x;   // 131072
    int b  = idx >> 14;
    int hw = idx & 16383;
    const float* p = x1 + (size_t)b * CC * HW1 + hw;
    float s = 0.f;
#pragma unroll
    for (int c = 0; c < CC; ++c) {
        float v = p[c * HW1];
        s += v * v;
    }
    inv1[idx] = 1.0f / sqrtf(s);
}

// 4-way channel-split inv-norm of x2 (450 blocks, LDS reduce)
__global__ __launch_bounds__(256) void k_inv2(const float* __restrict__ x2,
                                              float* __restrict__ inv2) {
    __shared__ float red[256];
    int tid = threadIdx.x;
    int pix = blockIdx.x * 64 + (tid & 63);     // 450*64 = 28800 exactly
    int csub = tid >> 6;
    int b  = pix / (HS * WS);
    int hw = pix % (HS * WS);
    const float* p = x2 + ((size_t)b * CC + csub * 16) * (HS * WS) + hw;
    float s = 0.f;
#pragma unroll
    for (int c = 0; c < 16; ++c) {
        float v = p[c * (HS * WS)];
        s += v * v;
    }
    red[tid] = s;
    __syncthreads();
    if (tid < 64) {
        float t = red[tid] + red[tid + 64] + red[tid + 128] + red[tid + 192];
        inv2[blockIdx.x * 64 + tid] = 1.0f / sqrtf(t);
    }
}

// fold 10x10 patch grid into 6x6 kernel per (b,c) via LDS scatter-bins
__global__ __launch_bounds__(256) void k_fold(const float* __restrict__ x2,
                                              const float* __restrict__ inv2,
                                              float* __restrict__ S) {
    __shared__ float bins[36];
    int tid = threadIdx.x;
    int bc  = blockIdx.x;            // 512 = b*64+c
    int b   = bc >> 6;
    if (tid < 36) bins[tid] = 0.f;
    __syncthreads();
    const float* px = x2 + (size_t)bc * (HS * WS);
    const float* pn = inv2 + b * (HS * WS);
    for (int i = tid; i < HS * WS; i += 256) {
        int hh = i / WS, ww = i - hh * WS;
        int bin = (hh % 6) * 6 + (ww % 6);
        atomicAdd(&bins[bin], px[i] * pn[i]);
    }
    __syncthreads();
    if (tid < 36) S[bc * 36 + tid] = bins[tid];
}

// ---------------------------------------------------------------------------
// conv: 64x32 output tile (+ guarded row/col 128), 4 channels per block,
// double-buffered LDS, register-blocked 4x2 outputs/thread via ds_read_b128
__global__ __launch_bounds__(256) void k_conv(const float* __restrict__ x1,
                                              const float* __restrict__ inv1,
                                              const float* __restrict__ S,
                                              float* __restrict__ part) {
    int blk = blockIdx.x;            // 2*4*8*16 = 1024
    int xt = blk & 1;
    int yt = (blk >> 1) & 3;
    int b  = (blk >> 3) & 7;
    int g  = blk >> 6;
    int x0 = xt * 64, y0 = yt * 32;
    int tid = threadIdx.x;
    int txq = tid & 15, ty = tid >> 4;

    __shared__ float buf[2][HR * HSTR];

    const float* x1b   = x1 + (size_t)b * CC * HW1;
    const float* inv1b = inv1 + b * HW1;

    // per-thread staging metadata (channel-invariant)
    int   goff[NST];
    float vinv[NST];
    int   lofs[NST];
#pragma unroll
    for (int k = 0; k < NST; ++k) {
        int i = tid + 256 * k;                 // valid slots: i < 2850
        int r  = i / HC;
        int cl = i - r * HC;
        int gy = y0 - 3 + r, gx = x0 - 3 + cl;
        bool v = (i < HR * HC) && gy >= 0 && gy < H1 && gx >= 0 && gx < W1;
        goff[k] = v ? gy * W1 + gx : 0;
        vinv[k] = v ? inv1b[gy * W1 + gx] : 0.0f;
        lofs[k] = (i < HR * HC) ? r * HSTR + cl : 0;
    }

    float acc0[5] = {0,0,0,0,0};
    float acc1[5] = {0,0,0,0,0};
    float acc2[5] = {0,0,0,0,0};
    const bool doR2 = (ty == 15) && (y0 == 96);   // extra output row 128
    const bool c5   = (x0 == 64) && (txq == 15);  // extra output col 128

    int ch0 = g * CPG;
    const float* Sb = S + ((size_t)b * CC + ch0) * 36;

    // prefetch channel 0
    float a[NST];
#pragma unroll
    for (int k = 0; k < NST; ++k)
        a[k] = x1b[(size_t)ch0 * HW1 + goff[k]] * vinv[k];

    for (int ci = 0; ci < CPG; ++ci) {
        float* bp = buf[ci & 1];
#pragma unroll
        for (int k = 0; k < NST; ++k) {
            if (k < 11) bp[lofs[k]] = a[k];
            else if (tid < (HR * HC - 11 * 256)) bp[lofs[k]] = a[k];
        }
        __syncthreads();

        if (ci + 1 < CPG) {
#pragma unroll
            for (int k = 0; k < NST; ++k)
                a[k] = x1b[(size_t)(ch0 + ci + 1) * HW1 + goff[k]] * vinv[k];
        }

        const float* Sc = Sb + ci * 36;        // uniform -> scalar loads
        float sv[36];
#pragma unroll
        for (int t = 0; t < 36; ++t) sv[t] = Sc[t];

        const float* base = bp + 4 * txq;
#pragma unroll
        for (int rr = 0; rr < 7; ++rr) {
            int row = 2 * ty + rr;
            const float4* rp = (const float4*)(base + row * HSTR);
            float4 q0 = rp[0], q1 = rp[1], q2 = rp[2];
            float r[12] = {q0.x,q0.y,q0.z,q0.w, q1.x,q1.y,q1.z,q1.w,
                           q2.x,q2.y,q2.z,q2.w};
            if (rr <= 5) {
#pragma unroll
                for (int j = 0; j < 5; ++j)
#pragma unroll
                    for (int dx = 0; dx < 6; ++dx)
                        acc0[j] += r[j + dx] * sv[rr * 6 + dx];
            }
            if (rr >= 1) {
#pragma unroll
                for (int j = 0; j < 5; ++j)
#pragma unroll
                    for (int dx = 0; dx < 6; ++dx)
                        acc1[j] += r[j + dx] * sv[(rr - 1) * 6 + dx];
            }
            if (doR2 && rr >= 2) {
#pragma unroll
                for (int j = 0; j < 5; ++j)
#pragma unroll
                    for (int dx = 0; dx < 6; ++dx)
                        acc2[j] += r[j + dx] * sv[(rr - 2) * 6 + dx];
            }
        }
        if (doR2) {   // window row 7 feeds only the extra output row
            int row = 2 * ty + 7;
            const float4* rp = (const float4*)(base + row * HSTR);
            float4 q0 = rp[0], q1 = rp[1], q2 = rp[2];
            float r[12] = {q0.x,q0.y,q0.z,q0.w, q1.x,q1.y,q1.z,q1.w,
                           q2.x,q2.y,q2.z,q2.w};
#pragma unroll
            for (int j = 0; j < 5; ++j)
#pragma unroll
                for (int dx = 0; dx < 6; ++dx)
                    acc2[j] += r[j + dx] * sv[5 * 6 + dx];
        }
    }

    float* pb = part + ((size_t)g * BB + b) * PPLANE;
    int orow = y0 + 2 * ty;
    int ocol = x0 + 4 * txq;
    *(float4*)(pb + (size_t)orow * PSTR + ocol) =
        make_float4(acc0[0], acc0[1], acc0[2], acc0[3]);
    *(float4*)(pb + (size_t)(orow + 1) * PSTR + ocol) =
        make_float4(acc1[0], acc1[1], acc1[2], acc1[3]);
    if (c5) {
        pb[(size_t)orow * PSTR + 128] = acc0[4];
        pb[(size_t)(orow + 1) * PSTR + 128] = acc1[4];
    }
    if (doR2) {
        *(float4*)(pb + (size_t)128 * PSTR + ocol) =
            make_float4(acc2[0], acc2[1], acc2[2], acc2[3]);
        if (c5) pb[(size_t)128 * PSTR + 128] = acc2[4];
    }
}

// reduce 16 partials -> out129 (applies 1/3600)
__global__ __launch_bounds__(256) void k_reduce(const float* __restrict__ part,
                                                float* __restrict__ out129) {
    int idx = blockIdx.x * 256 + threadIdx.x;   // 8*129*129 = 133128
    if (idx >= BB * HO * WO) return;
    int b = idx / (HO * WO);
    int p = idx % (HO * WO);
    int row = p / WO, col = p - row * WO;
    float s = 0.f;
#pragma unroll
    for (int g = 0; g < G; ++g)
        s += part[((size_t)g * BB + b) * PPLANE + (size_t)row * PSTR + col];
    out129[idx] = s * (1.0f / 3600.0f);
}

// jax.image.resize bilinear antialias=True, 129 -> 128, half-pixel
__global__ __launch_bounds__(256) void k_resize(const float* __restrict__ out129,
                                                float* __restrict__ out) {
    int idx = blockIdx.x * 256 + threadIdx.x;   // 131072
    int b  = idx >> 14;
    int oy = (idx >> 7) & 127;
    int ox = idx & 127;

    const float inv_scale = 129.0f / 128.0f;
    const float ksc       = 128.0f / 129.0f;

    float sy = (oy + 0.5f) * inv_scale - 0.5f;
    float sx = (ox + 0.5f) * inv_scale - 0.5f;
    int fy = (int)floorf(sy);
    int fx = (int)floorf(sx);

    float wy[4], wx[4];
    float sumy = 0.f, sumx = 0.f;
#pragma unroll
    for (int k = 0; k < 4; ++k) {
        int jy = fy - 1 + k;
        float w = 0.f;
        if (jy >= 0 && jy < HO) w = fmaxf(0.f, 1.0f - fabsf(sy - (float)jy) * ksc);
        wy[k] = w; sumy += w;
        int jx = fx - 1 + k;
        float w2 = 0.f;
        if (jx >= 0 && jx < WO) w2 = fmaxf(0.f, 1.0f - fabsf(sx - (float)jx) * ksc);
        wx[k] = w2; sumx += w2;
    }

    const float* p = out129 + (size_t)b * (HO * WO);
    float r = 0.f;
#pragma unroll
    for (int ky = 0; ky < 4; ++ky) {
        if (wy[ky] == 0.f) continue;
        int jy = fy - 1 + ky;
        float rowv = 0.f;
#pragma unroll
        for (int kx = 0; kx < 4; ++kx) {
            if (wx[kx] == 0.f) continue;
            rowv += wx[kx] * p[jy * WO + (fx - 1 + kx)];
        }
        r += wy[ky] * rowv;
    }
    out[idx] = r / (sumy * sumx);
}

// ---------------------------------------------------------------------------
extern "C" void kernel_launch(void* const* d_in, const int* in_sizes, int n_in,
                              void* d_out, int out_size, void* d_ws, size_t ws_size,
                              hipStream_t stream) {
    const float* x1 = (const float*)d_in[0];   // (8,64,128,128)
    const float* x2 = (const float*)d_in[1];   // (8,64,60,60)
    float* out = (float*)d_out;

    float* ws     = (float*)d_ws;
    float* inv1   = ws;                               // 131072
    float* inv2   = inv1 + BB * HW1;                  // 28800
    float* Sbuf   = inv2 + BB * HS * WS;              // 18432
    float* part   = Sbuf + BB * CC * 36;              // 16*8*17028 = 2179584
    float* out129 = part + (size_t)G * BB * PPLANE;   // 133128

    k_inv1  <<<(BB * HW1) / 256, 256, 0, stream>>>(x1, inv1);
    k_inv2  <<<(BB * HS * WS) / 64, 256, 0, stream>>>(x2, inv2);
    k_fold  <<<BB * CC, 256, 0, stream>>>(x2, inv2, Sbuf);
    k_conv  <<<2 * 4 * BB * G, 256, 0, stream>>>(x1, inv1, Sbuf, part);
    k_reduce<<<(BB * HO * WO + 255) / 256, 256, 0, stream>>>(part, out129);
    k_resize<<<(BB * HW1) / 256, 256, 0, stream>>>(out129, out);
}